// Round 1
// baseline (439.852 us; speedup 1.0000x reference)
//
#include <hip/hip_runtime.h>
#include <stdint.h>

#define CC    128
#define CQn   32
#define DD    32
#define IMG_H 96
#define IMG_W 320
#define HW    30720
#define NPIX  61440

// workspace byte offsets
#define OFF_Q    0
#define OFF_K    7864320
#define OFF_SIM  15728640
#define OFF_FUSED 0            // aliases q/k after K2 is done
#define OFF_WC   23592960
#define OFF_ST   23887872

__device__ __forceinline__ float bf2f(unsigned short u){
  union { unsigned int i; float f; } v; v.i = ((unsigned int)u) << 16; return v.f;
}
__device__ __forceinline__ unsigned short f2bf(float f){
  union { float f; unsigned int i; } v; v.f = f;
  unsigned int u = v.i;
  unsigned int r = u + 0x7fffu + ((u >> 16) & 1u);
  return (unsigned short)(r >> 16);
}

// ---------------- K0: weight prep ----------------
__global__ __launch_bounds__(256) void k0_prep(
    const float* __restrict__ rc_w, const float* __restrict__ ce_w, const float* __restrict__ ce_b,
    const float* __restrict__ fa_w, const float* __restrict__ nt_w, const float* __restrict__ nt_b,
    unsigned short* __restrict__ wconv, float* __restrict__ gbuf){
  int blk = blockIdx.x;
  if (blk < 576){
    int idx = blk * 256 + threadIdx.x;           // 0..147455
    int o = idx / 1152;
    int r = idx - o * 1152;
    int pos = r >> 7;
    int c = r & 127;
    wconv[idx] = f2bf(rc_w[(o * 128 + c) * 9 + pos]);
  } else {
    int t = threadIdx.x;
    if (t < 32){
      float a = 0.f;
      for (int o = 0; o < 128; o++) a += fa_w[128 + o] * ce_w[o * 32 + t];
      gbuf[t] = a;
    } else if (t == 32){
      float a = 0.f;
      for (int o = 0; o < 128; o++) a += fa_w[128 + o] * ce_b[o];
      gbuf[32] = a;
    } else if (t == 33){
      float a = 0.f;
      for (int c = 0; c < 128; c++) a += fa_w[c] * nt_w[c];
      gbuf[33] = a;
    } else if (t == 34){
      float a = 0.f;
      for (int c = 0; c < 128; c++) a += fa_w[c] * nt_b[c];
      gbuf[34] = a;
    }
  }
}

// ---------------- K1: q/k projection + t_feat stats ----------------
__global__ __launch_bounds__(256) void k1_qk(
    const float* __restrict__ t_feat, const float* __restrict__ s_feat,
    const float* __restrict__ q_w, const float* __restrict__ q_b,
    const float* __restrict__ k_w, const float* __restrict__ k_b,
    float* __restrict__ q_out, float* __restrict__ k_out,
    double* __restrict__ tsum, double* __restrict__ tsq){
  __shared__ __align__(16) float qw[4096];
  __shared__ __align__(16) float kw[4096];
  __shared__ float red1[4], red2[4];
  int tid = threadIdx.x;
  for (int i = tid; i < 4096; i += 256){ qw[i] = q_w[i]; kw[i] = k_w[i]; }
  __syncthreads();
  int b = blockIdx.y;
  int pix = blockIdx.x * 256 + tid;              // 0..30719
  const float* tf = t_feat + b * CC * HW + pix;
  const float* sf = s_feat + b * CC * HW + pix;
  float qa[32], ka[32];
  #pragma unroll
  for (int o = 0; o < 32; o++){ qa[o] = q_b[o]; ka[o] = k_b[o]; }
  float s1 = 0.f, s2 = 0.f;
  for (int c0 = 0; c0 < 128; c0 += 4){
    float tv0 = tf[(c0+0)*HW], tv1 = tf[(c0+1)*HW], tv2 = tf[(c0+2)*HW], tv3 = tf[(c0+3)*HW];
    float sv0 = sf[(c0+0)*HW], sv1 = sf[(c0+1)*HW], sv2 = sf[(c0+2)*HW], sv3 = sf[(c0+3)*HW];
    s1 += tv0 + tv1 + tv2 + tv3;
    s2 += tv0*tv0 + tv1*tv1 + tv2*tv2 + tv3*tv3;
    #pragma unroll
    for (int o = 0; o < 32; o++){
      const float4 wq = *(const float4*)&qw[o*128 + c0];
      const float4 wk = *(const float4*)&kw[o*128 + c0];
      qa[o] += wq.x*tv0 + wq.y*tv1 + wq.z*tv2 + wq.w*tv3;
      ka[o] += wk.x*sv0 + wk.y*sv1 + wk.z*sv2 + wk.w*sv3;
    }
  }
  float* qo = q_out + b * CQn * HW + pix;
  float* ko = k_out + b * CQn * HW + pix;
  #pragma unroll
  for (int o = 0; o < 32; o++){ qo[o*HW] = qa[o]; ko[o*HW] = ka[o]; }
  #pragma unroll
  for (int off = 32; off > 0; off >>= 1){ s1 += __shfl_down(s1, off, 64); s2 += __shfl_down(s2, off, 64); }
  int lane = tid & 63, wid = tid >> 6;
  if (lane == 0){ red1[wid] = s1; red2[wid] = s2; }
  __syncthreads();
  if (tid == 0){
    double a1 = (double)red1[0] + red1[1] + red1[2] + red1[3];
    double a2 = (double)red2[0] + red2[1] + red2[2] + red2[3];
    atomicAdd(&tsum[b], a1);
    atomicAdd(&tsq[b], a2);
  }
}

// ---------------- K2: warp + cosine sim volume ----------------
__global__ __launch_bounds__(320) void k2_sim(
    const float* __restrict__ q, const float* __restrict__ k,
    const float* __restrict__ directs, const float* __restrict__ disp,
    float* __restrict__ sim){
  __shared__ unsigned short klds[IMG_W * 34];
  __shared__ float displ[32];
  int tid = threadIdx.x;
  int b = blockIdx.y, h = blockIdx.x;
  const float* krow = k + b * CQn * HW + h * IMG_W;
  for (int idx = tid; idx < CQn * IMG_W; idx += 320){
    int c = idx / IMG_W, x = idx - c * IMG_W;
    klds[x * 34 + c] = f2bf(krow[c * HW + x]);
  }
  if (tid < 32) displ[tid] = disp[tid];
  __syncthreads();
  int w = tid;
  float direct = directs[b];
  const float* qcol = q + b * CQn * HW + h * IMG_W + w;
  float qreg[32];
  float nq2 = 0.f;
  #pragma unroll
  for (int c = 0; c < 32; c++){ float v = qcol[c*HW]; qreg[c] = v; nq2 += v*v; }
  float inv_q = 1.0f / fmaxf(sqrtf(nq2), 1e-12f);
  float* simb = sim + b * DD * HW + h * IMG_W + w;
  for (int d = 0; d < 32; d++){
    float pos = (float)w + displ[d] * direct * (float)(IMG_W - 1);
    pos = fminf(fmaxf(pos, 0.0f), (float)(IMG_W - 1));
    int x0 = (int)pos;                       // floor (pos >= 0)
    int x1 = min(x0 + 1, IMG_W - 1);
    float t = pos - (float)x0;
    const unsigned short* k0p = &klds[x0 * 34];
    const unsigned short* k1p = &klds[x1 * 34];
    float dot = 0.f, n2 = 0.f;
    #pragma unroll
    for (int c = 0; c < 32; c++){
      float k0 = bf2f(k0p[c]);
      float k1 = bf2f(k1p[c]);
      float wv = k0 + t * (k1 - k0);
      dot += qreg[c] * wv;
      n2  += wv * wv;
    }
    simb[d * HW] = dot * inv_q / fmaxf(sqrtf(n2), 1e-12f);
  }
}

// ---------------- K3: 3x3x3 cost conv + softmax_d + stats ----------------
__global__ __launch_bounds__(320) void k3_cost(
    const float* __restrict__ sim, const float* __restrict__ cf_w,
    float* __restrict__ norm_cost, double* __restrict__ csum, double* __restrict__ csq){
  __shared__ float w3[27];
  __shared__ float red1[5], red2[5];
  int tid = threadIdx.x;
  if (tid < 27) w3[tid] = cf_w[tid];
  __syncthreads();
  int b = blockIdx.y, h = blockIdx.x, w = tid;
  float cost[32];
  #pragma unroll
  for (int d = 0; d < 32; d++) cost[d] = 0.f;
  const float* sb = sim + b * DD * HW;
  #pragma unroll
  for (int i = 0; i < 3; i++){
    int hh = h + i - 1;
    if (hh < 0 || hh >= IMG_H) continue;     // wave-uniform
    #pragma unroll
    for (int j = 0; j < 3; j++){
      int ww = w + j - 1;
      bool ok = (ww >= 0 && ww < IMG_W);
      const float* col = sb + hh * IMG_W + (ok ? ww : 0);
      float w0 = w3[0*9 + i*3 + j], w1 = w3[1*9 + i*3 + j], w2 = w3[2*9 + i*3 + j];
      #pragma unroll
      for (int e = 0; e < 32; e++){
        float v = ok ? col[e * HW] : 0.f;
        if (e < 31) cost[e+1] += w0 * v;
        cost[e] += w1 * v;
        if (e > 0)  cost[e-1] += w2 * v;
      }
    }
  }
  float mx = cost[0];
  #pragma unroll
  for (int d = 1; d < 32; d++) mx = fmaxf(mx, cost[d]);
  float s = 0.f;
  #pragma unroll
  for (int d = 0; d < 32; d++){ cost[d] = expf(cost[d] - mx); s += cost[d]; }
  float inv = 1.0f / s;
  float s1 = 0.f, s2 = 0.f;
  float* nb = norm_cost + b * DD * HW + h * IMG_W + w;
  #pragma unroll
  for (int d = 0; d < 32; d++){
    float nc = cost[d] * inv;
    nb[d * HW] = nc;
    s1 += nc; s2 += nc * nc;
  }
  #pragma unroll
  for (int off = 32; off > 0; off >>= 1){ s1 += __shfl_down(s1, off, 64); s2 += __shfl_down(s2, off, 64); }
  int lane = tid & 63, wid = tid >> 6;
  if (lane == 0){ red1[wid] = s1; red2[wid] = s2; }
  __syncthreads();
  if (tid == 0){
    double a1 = 0, a2 = 0;
    for (int i = 0; i < 5; i++){ a1 += red1[i]; a2 += red2[i]; }
    atomicAdd(&csum[b], a1);
    atomicAdd(&csq[b], a2);
  }
}

// ---------------- K4: groupnorms + cost embed + gated fusion -> fused bf16 [pix][c] ----------------
__global__ __launch_bounds__(256) void k4_fuse(
    const float* __restrict__ t_feat, const float* __restrict__ norm_cost,
    const float* __restrict__ nt_w, const float* __restrict__ nt_b,
    const float* __restrict__ nc_w, const float* __restrict__ nc_b,
    const float* __restrict__ ce_w, const float* __restrict__ ce_b,
    const float* __restrict__ fa_w, const float* __restrict__ fa_b,
    const double* __restrict__ tsum, const double* __restrict__ tsq,
    const double* __restrict__ csum, const double* __restrict__ csq,
    const float* __restrict__ gbuf, unsigned short* __restrict__ fused){
  __shared__ __align__(16) float ce[4096];
  __shared__ float ntw[128], ntb[128], fa1[128], ceb[128];
  __shared__ float ncw[32], ncb[32], gg[32];
  int tid = threadIdx.x;
  for (int i = tid; i < 4096; i += 256) ce[i] = ce_w[i];
  if (tid < 128){ ntw[tid] = nt_w[tid]; ntb[tid] = nt_b[tid]; fa1[tid] = fa_w[tid]; ceb[tid] = ce_b[tid]; }
  if (tid < 32){ ncw[tid] = nc_w[tid]; ncb[tid] = nc_b[tid]; gg[tid] = gbuf[tid]; }
  __syncthreads();
  int P = blockIdx.x * 256 + tid;               // 0..61439
  int b = P / HW;
  int pix = P - b * HW;
  float mu_t  = (float)(tsum[b] * (1.0 / (128.0 * HW)));
  float var_t = (float)(tsq[b]  * (1.0 / (128.0 * HW))) - mu_t * mu_t;
  float inv_t = 1.0f / sqrtf(var_t + 1e-5f);
  float mu_c  = (float)(csum[b] * (1.0 / (32.0 * HW)));
  float var_c = (float)(csq[b]  * (1.0 / (32.0 * HW))) - mu_c * mu_c;
  float inv_c = 1.0f / sqrtf(var_c + 1e-5f);
  const float* ncp = norm_cost + b * DD * HW + pix;
  float cn[32];
  float dg = 0.f;
  #pragma unroll
  for (int d = 0; d < 32; d++){
    float v = ncp[d * HW];
    float c = (v - mu_c) * inv_c * ncw[d] + ncb[d];
    cn[d] = c;
    dg += gg[d] * c;
  }
  const float* tfp = t_feat + b * CC * HW + pix;
  float dott = 0.f;
  for (int c = 0; c < 128; c++) dott += fa1[c] * ntw[c] * tfp[c * HW];
  float z = dg + gbuf[32] + inv_t * dott - mu_t * inv_t * gbuf[33] + gbuf[34] + fa_b[0];
  float alpha = 1.0f / (1.0f + expf(-z));
  float beta = 1.0f - alpha;
  unsigned short* fp = fused + (size_t)P * 128;
  for (int c0 = 0; c0 < 128; c0 += 8){
    __align__(16) unsigned short buf[8];
    #pragma unroll
    for (int jj = 0; jj < 8; jj++){
      int c = c0 + jj;
      float tv = tfp[c * HW];
      float tn = (tv - mu_t) * inv_t * ntw[c] + ntb[c];
      float cf = ceb[c];
      const float4* cw = (const float4*)&ce[c * 32];
      #pragma unroll
      for (int d4 = 0; d4 < 8; d4++){
        float4 wv = cw[d4];
        cf += wv.x * cn[d4*4+0] + wv.y * cn[d4*4+1] + wv.z * cn[d4*4+2] + wv.w * cn[d4*4+3];
      }
      float f = alpha * tn + beta * cf;
      buf[jj] = f2bf(f);
    }
    *(uint4*)(fp + c0) = *(const uint4*)buf;
  }
}

// ---------------- K5: 3x3 reflect conv 128->128 via MFMA + SE partial sums ----------------
typedef __bf16 bf16x8 __attribute__((ext_vector_type(8)));
typedef float  f32x4  __attribute__((ext_vector_type(4)));

__global__ __launch_bounds__(256) void k5_conv(
    const unsigned short* __restrict__ fused, const unsigned short* __restrict__ wconv,
    const float* __restrict__ rc_b, float* __restrict__ xout, float* __restrict__ ysum){
  __shared__ __align__(16) unsigned short patch[6 * 18 * 136];   // [row][col][c], c-stride 136
  __shared__ __align__(16) unsigned short wch[4096];             // [kq][o][8]
  __shared__ float rcb[128];
  int tid = threadIdx.x;
  int b = blockIdx.z;
  int h0 = blockIdx.y * 4;
  int w0 = blockIdx.x * 16;
  if (tid < 128) rcb[tid] = rc_b[tid];
  for (int idx = tid; idx < 108 * 16; idx += 256){
    int pp = idx >> 4, j = idx & 15;
    int r = pp / 18, col = pp - r * 18;
    int hs = h0 + r - 1;  hs  = hs  < 0 ? -hs  : (hs  >= IMG_H ? 2*IMG_H - 2 - hs  : hs);
    int ws2 = w0 + col - 1; ws2 = ws2 < 0 ? -ws2 : (ws2 >= IMG_W ? 2*IMG_W - 2 - ws2 : ws2);
    const uint4* src = (const uint4*)(fused + (size_t)((b * IMG_H + hs) * IMG_W + ws2) * 128 + j * 8);
    *(uint4*)&patch[(r * 18 + col) * 136 + j * 8] = *src;
  }
  int wid = tid >> 6, lane = tid & 63;
  int quad = lane >> 4, l15 = lane & 15;
  f32x4 acc[2][4];
  #pragma unroll
  for (int m = 0; m < 2; m++)
    #pragma unroll
    for (int nt = 0; nt < 4; nt++)
      acc[m][nt] = (f32x4){0.f, 0.f, 0.f, 0.f};
  for (int pos = 0; pos < 9; pos++){
    int kh = pos / 3;
    int kw2 = pos - kh * 3;
    #pragma unroll
    for (int q4 = 0; q4 < 4; q4++){
      int koff = pos * 128 + q4 * 32;
      __syncthreads();
      #pragma unroll
      for (int it = 0; it < 2; it++){
        int idx = it * 256 + tid;               // 0..511
        int kq = idx >> 7, o = idx & 127;
        *(uint4*)&wch[(kq * 128 + o) * 8] = *(const uint4*)(wconv + o * 1152 + koff + kq * 8);
      }
      __syncthreads();
      bf16x8 a0 = *(const bf16x8*)&wch[(quad * 128 + wid * 32 + l15) * 8];
      bf16x8 a1 = *(const bf16x8*)&wch[(quad * 128 + wid * 32 + 16 + l15) * 8];
      #pragma unroll
      for (int nt = 0; nt < 4; nt++){
        bf16x8 bf = *(const bf16x8*)&patch[((nt + kh) * 18 + l15 + kw2) * 136 + q4 * 32 + quad * 8];
        acc[0][nt] = __builtin_amdgcn_mfma_f32_16x16x32_bf16(a0, bf, acc[0][nt], 0, 0, 0);
        acc[1][nt] = __builtin_amdgcn_mfma_f32_16x16x32_bf16(a1, bf, acc[1][nt], 0, 0, 0);
      }
    }
  }
  #pragma unroll
  for (int m = 0; m < 2; m++){
    float ys[4] = {0.f, 0.f, 0.f, 0.f};
    #pragma unroll
    for (int nt = 0; nt < 4; nt++){
      #pragma unroll
      for (int r = 0; r < 4; r++){
        int o = wid * 32 + m * 16 + quad * 4 + r;
        float v = acc[m][nt][r] + rcb[o];
        xout[((size_t)(b * CC + o) * IMG_H + (h0 + nt)) * IMG_W + w0 + l15] = v;
        float rv = v;
        rv += __shfl_xor(rv, 1, 64);
        rv += __shfl_xor(rv, 2, 64);
        rv += __shfl_xor(rv, 4, 64);
        rv += __shfl_xor(rv, 8, 64);
        ys[r] += rv;
      }
    }
    if (l15 == 0){
      int ob = wid * 32 + m * 16 + quad * 4;
      #pragma unroll
      for (int r = 0; r < 4; r++) atomicAdd(&ysum[b * CC + ob + r], ys[r]);
    }
  }
}

// ---------------- K6: SE MLP ----------------
__global__ __launch_bounds__(256) void k6_se(
    const float* __restrict__ ysum, const float* __restrict__ se_w1,
    const float* __restrict__ se_w2, float* __restrict__ sescale){
  __shared__ float ym[256];
  __shared__ float y1[16];
  int t = threadIdx.x;
  ym[t] = ysum[t] * (1.0f / (float)HW);
  __syncthreads();
  if (t < 16){
    int b = t >> 3, j = t & 7;
    float a = 0.f;
    for (int o = 0; o < 128; o++) a += ym[b * 128 + o] * se_w1[j * 128 + o];
    y1[t] = fmaxf(a, 0.f);
  }
  __syncthreads();
  int b = t >> 7, o = t & 127;
  float a = 0.f;
  #pragma unroll
  for (int j = 0; j < 8; j++) a += y1[b * 8 + j] * se_w2[o * 8 + j];
  sescale[t] = 1.0f / (1.0f + expf(-a));
}

// ---------------- K7: x = elu(x * scale), in place ----------------
__global__ __launch_bounds__(256) void k7_elu(float* __restrict__ x, const float* __restrict__ sescale){
  int i4 = blockIdx.x * 256 + threadIdx.x;      // 0..1966079
  float4* xp = (float4*)x;
  float4 v = xp[i4];
  float s = sescale[i4 / 7680];                 // 30720/4 per (b,o)
  float a = v.x * s, bb = v.y * s, c = v.z * s, d = v.w * s;
  v.x = a  > 0.f ? a  : expm1f(a);
  v.y = bb > 0.f ? bb : expm1f(bb);
  v.z = c  > 0.f ? c  : expm1f(c);
  v.w = d  > 0.f ? d  : expm1f(d);
  xp[i4] = v;
}

extern "C" void kernel_launch(void* const* d_in, const int* in_sizes, int n_in,
                              void* d_out, int out_size, void* d_ws, size_t ws_size,
                              hipStream_t stream){
  const float* t_feat = (const float*)d_in[0];
  const float* s_feat = (const float*)d_in[1];
  const float* directs = (const float*)d_in[2];
  const float* disp   = (const float*)d_in[3];
  const float* q_w = (const float*)d_in[4];
  const float* q_b = (const float*)d_in[5];
  const float* k_w = (const float*)d_in[6];
  const float* k_b = (const float*)d_in[7];
  const float* cf_w = (const float*)d_in[8];
  // d_in[9] = cf_b: softmax is shift-invariant, unused
  const float* nt_w = (const float*)d_in[10];
  const float* nt_b = (const float*)d_in[11];
  const float* nc_w = (const float*)d_in[12];
  const float* nc_b = (const float*)d_in[13];
  const float* ce_w = (const float*)d_in[14];
  const float* ce_b = (const float*)d_in[15];
  const float* fa_w = (const float*)d_in[16];
  const float* fa_b = (const float*)d_in[17];
  const float* rc_w = (const float*)d_in[18];
  const float* rc_b = (const float*)d_in[19];
  const float* se_w1 = (const float*)d_in[20];
  const float* se_w2 = (const float*)d_in[21];

  char* ws = (char*)d_ws;
  float* q_out = (float*)(ws + OFF_Q);
  float* k_out = (float*)(ws + OFF_K);
  float* sim   = (float*)(ws + OFF_SIM);
  unsigned short* fused = (unsigned short*)(ws + OFF_FUSED);
  unsigned short* wconv = (unsigned short*)(ws + OFF_WC);
  char* st = ws + OFF_ST;
  double* tsum = (double*)(st + 0);
  double* tsq  = (double*)(st + 16);
  double* csum = (double*)(st + 32);
  double* csq  = (double*)(st + 48);
  float* ysum  = (float*)(st + 64);      // 256 f32
  float* sescale = (float*)(st + 1088);  // 256 f32
  float* gbuf  = (float*)(st + 2112);    // 35 f32

  float* xout = (float*)d_out;
  float* norm_cost = (float*)d_out + 7864320;

  hipMemsetAsync(st, 0, 1088, stream);
  k0_prep<<<577, 256, 0, stream>>>(rc_w, ce_w, ce_b, fa_w, nt_w, nt_b, wconv, gbuf);
  k1_qk<<<dim3(120, 2), 256, 0, stream>>>(t_feat, s_feat, q_w, q_b, k_w, k_b, q_out, k_out, tsum, tsq);
  k2_sim<<<dim3(96, 2), 320, 0, stream>>>(q_out, k_out, directs, disp, sim);
  k3_cost<<<dim3(96, 2), 320, 0, stream>>>(sim, cf_w, norm_cost, csum, csq);
  k4_fuse<<<240, 256, 0, stream>>>(t_feat, norm_cost, nt_w, nt_b, nc_w, nc_b, ce_w, ce_b,
                                   fa_w, fa_b, tsum, tsq, csum, csq, gbuf, fused);
  k5_conv<<<dim3(20, 24, 2), 256, 0, stream>>>(fused, wconv, rc_b, xout, ysum);
  k6_se<<<1, 256, 0, stream>>>(ysum, se_w1, se_w2, sescale);
  k7_elu<<<7680, 256, 0, stream>>>(xout, sescale);
}

// Round 2
// 343.115 us; speedup vs baseline: 1.2819x; 1.2819x over previous
//
#include <hip/hip_runtime.h>
#include <stdint.h>

#define CC    128
#define CQn   32
#define DD    32
#define IMG_H 96
#define IMG_W 320
#define HW    30720
#define NPIX  61440

// workspace byte offsets (peak ~20.0 MB, proven ws >= 23.9 MB last round)
#define OFF_Q     0            // q f16 [2][30720][32]  = 3,932,160 B
#define OFF_K     3932160      // k f16                 = 3,932,160 B
#define OFF_SIM   7864320      // sim f32 [2][32][96][320] = 7,864,320 B
#define OFF_NCP   15728640     // norm_cost f16 [2][30720][32] = 3,932,160 B
#define OFF_FUSED 0            // fused f16 [61440][128] = 15,728,640 B (aliases q/k/sim)
#define OFF_WC    19660800     // conv weights f16, 294,912 B
#define OFF_WQK   19955712     // q_w/k_w f16, 16,384 B
#define OFF_AP    19972096     // A' f16 [2][128][32], 16,384 B
#define OFF_MISC  19988480     // f32: biasp[256],tnA[256],tnB[256],h1g[256],gp[64],zc[2]
#define OFF_ST    20000768     // stats

typedef _Float16 half_t;
typedef _Float16 f16x2 __attribute__((ext_vector_type(2)));
typedef _Float16 f16x8 __attribute__((ext_vector_type(8)));
typedef float    f32x4 __attribute__((ext_vector_type(4)));

__device__ __forceinline__ float fdot2f(f16x2 a, f16x2 b, float c){
#if __has_builtin(__builtin_amdgcn_fdot2)
  return __builtin_amdgcn_fdot2(a, b, c, false);
#else
  return c + (float)a.x*(float)b.x + (float)a.y*(float)b.y;
#endif
}

__device__ __forceinline__ void gld16(const half_t* g, half_t* l){
#if __has_builtin(__builtin_amdgcn_global_load_lds)
  __builtin_amdgcn_global_load_lds(
      (const __attribute__((address_space(1))) unsigned int*)g,
      (__attribute__((address_space(3))) unsigned int*)l, 16, 0, 0);
#else
  *(uint4*)l = *(const uint4*)g;
#endif
}

// ---------------- K0: weight prep (conv weights re-layout + qk weights f16 + gate constants) ----
__global__ __launch_bounds__(256) void k0_prep(
    const float* __restrict__ rc_w, const float* __restrict__ q_w, const float* __restrict__ k_w,
    const float* __restrict__ ce_w, const float* __restrict__ ce_b,
    const float* __restrict__ fa_w, const float* __restrict__ nt_w, const float* __restrict__ nt_b,
    half_t* __restrict__ wconv, half_t* __restrict__ wqk, float* __restrict__ gbuf){
  int blk = blockIdx.x, tid = threadIdx.x;
  if (blk < 576){
    // wconv[((pos*16 + q4*4 + kq)*128 + o)*8 + j] = rc_w[o][c][pos], c = q4*32+kq*8+j
    int idx = blk * 256 + tid;                 // 0..147455
    int j = idx & 7;
    int o = (idx >> 3) & 127;
    int g = idx >> 10;                          // 0..143
    int kq = g & 3, q4 = (g >> 2) & 3, pos = g >> 4;
    int c = q4*32 + kq*8 + j;
    wconv[idx] = (half_t)rc_w[(o*128 + c)*9 + pos];
  } else if (blk < 608){
    int idx = (blk - 576) * 256 + tid;          // 0..8191
    wqk[idx] = (half_t)(idx < 4096 ? q_w[idx] : k_w[idx - 4096]);
  } else {
    int t = tid;
    if (t < 32){
      float a = 0.f;
      for (int o = 0; o < 128; o++) a += fa_w[128 + o] * ce_w[o * 32 + t];
      gbuf[t] = a;
    } else if (t == 32){
      float a = 0.f;
      for (int o = 0; o < 128; o++) a += fa_w[128 + o] * ce_b[o];
      gbuf[32] = a;
    } else if (t == 33){
      float a = 0.f;
      for (int c = 0; c < 128; c++) a += fa_w[c] * nt_w[c];
      gbuf[33] = a;
    } else if (t == 34){
      float a = 0.f;
      for (int c = 0; c < 128; c++) a += fa_w[c] * nt_b[c];
      gbuf[34] = a;
    }
  }
}

// ---------------- K1: q/k projections via MFMA + t_feat stats -> q,k f16 [b][pix][32] ---------
__global__ __launch_bounds__(256) void k1_qk(
    const float* __restrict__ t_feat, const float* __restrict__ s_feat,
    const half_t* __restrict__ wqk, const float* __restrict__ q_b, const float* __restrict__ k_b,
    half_t* __restrict__ qbuf, half_t* __restrict__ kbuf,
    double* __restrict__ tsum, double* __restrict__ tsq){
  __shared__ half_t feat[256 * 136];    // [px][c] pad 136
  __shared__ half_t outs[256 * 40];     // [px][o] pad 40
  __shared__ float red1[4], red2[4];
  __shared__ float qbl[32], kbl[32];
  int tid = threadIdx.x;
  int b = blockIdx.x / 120;
  int pix0 = (blockIdx.x % 120) * 256;
  int lane = tid & 63, wid = tid >> 6;
  int quad = lane >> 4, l15 = lane & 15;
  if (tid < 32){ qbl[tid] = q_b[tid]; kbl[tid] = k_b[tid]; }

  for (int phase = 0; phase < 2; phase++){
    const float* src = (phase == 0 ? t_feat : s_feat) + (size_t)b * CC * HW + pix0 + tid;
    float s1 = 0.f, s2 = 0.f;
    for (int c = 0; c < 128; c += 2){
      float v0 = src[c * HW], v1 = src[(c + 1) * HW];
      if (phase == 0){ s1 += v0 + v1; s2 += v0 * v0 + v1 * v1; }
      *(f16x2*)&feat[tid * 136 + c] = f16x2{(half_t)v0, (half_t)v1};
    }
    if (phase == 0){
      #pragma unroll
      for (int off = 32; off > 0; off >>= 1){ s1 += __shfl_down(s1, off, 64); s2 += __shfl_down(s2, off, 64); }
      if (lane == 0){ red1[wid] = s1; red2[wid] = s2; }
    }
    __syncthreads();
    if (phase == 0 && tid == 0){
      atomicAdd(&tsum[b], (double)red1[0] + red1[1] + red1[2] + red1[3]);
      atomicAdd(&tsq[b],  (double)red2[0] + red2[1] + red2[2] + red2[3]);
    }
    const half_t* W = wqk + phase * 4096;
    f32x4 acc[2][4];
    #pragma unroll
    for (int m = 0; m < 2; m++)
      #pragma unroll
      for (int nt = 0; nt < 4; nt++) acc[m][nt] = (f32x4){0.f,0.f,0.f,0.f};
    #pragma unroll
    for (int q4 = 0; q4 < 4; q4++){
      f16x8 a0 = *(const f16x8*)&W[(l15) * 128 + q4*32 + quad*8];
      f16x8 a1 = *(const f16x8*)&W[(16 + l15) * 128 + q4*32 + quad*8];
      #pragma unroll
      for (int nt = 0; nt < 4; nt++){
        f16x8 bf = *(const f16x8*)&feat[(wid*64 + nt*16 + l15) * 136 + q4*32 + quad*8];
        acc[0][nt] = __builtin_amdgcn_mfma_f32_16x16x32_f16(a0, bf, acc[0][nt], 0, 0, 0);
        acc[1][nt] = __builtin_amdgcn_mfma_f32_16x16x32_f16(a1, bf, acc[1][nt], 0, 0, 0);
      }
    }
    const float* bl = phase == 0 ? qbl : kbl;
    #pragma unroll
    for (int m = 0; m < 2; m++)
      #pragma unroll
      for (int nt = 0; nt < 4; nt++)
        #pragma unroll
        for (int r = 0; r < 4; r++){
          int o = m*16 + quad*4 + r;
          outs[(wid*64 + nt*16 + l15) * 40 + o] = (half_t)(acc[m][nt][r] + bl[o]);
        }
    __syncthreads();
    {
      half_t* dst = (phase == 0 ? qbuf : kbuf) + (size_t)(b * HW + pix0 + tid) * 32;
      uint4* d4 = (uint4*)dst;
      const uint4* s4 = (const uint4*)&outs[tid * 40];
      d4[0] = s4[0]; d4[1] = s4[1]; d4[2] = s4[2]; d4[3] = s4[3];
    }
    __syncthreads();
  }
}

// ---------------- K2: warp + cosine sim volume (f16 packed math) ----------------
__global__ __launch_bounds__(320) void k2_sim(
    const half_t* __restrict__ qbuf, const half_t* __restrict__ kbuf,
    const float* __restrict__ directs, const float* __restrict__ disp,
    float* __restrict__ sim){
  __shared__ uint4 klds4[320 * 5];     // [x][4 data + 1 pad] = 64B rows padded to 80B
  __shared__ float displ[32];
  int tid = threadIdx.x;
  int b = blockIdx.y, h = blockIdx.x;
  for (int u = tid; u < 1280; u += 320){
    int x = u >> 2, j = u & 3;
    klds4[x * 5 + j] = ((const uint4*)(kbuf + (size_t)(b * HW + h * IMG_W + x) * 32))[j];
  }
  if (tid < 32) displ[tid] = disp[tid];
  __syncthreads();
  int w = tid;
  float direct = directs[b];
  union U16 { uint4 u4[4]; f16x2 h2[16]; };
  U16 qu;
  {
    const uint4* qp = (const uint4*)(qbuf + (size_t)(b * HW + h * IMG_W + w) * 32);
    qu.u4[0] = qp[0]; qu.u4[1] = qp[1]; qu.u4[2] = qp[2]; qu.u4[3] = qp[3];
  }
  float nq2 = 0.f;
  #pragma unroll
  for (int i = 0; i < 16; i++) nq2 = fdot2f(qu.h2[i], qu.h2[i], nq2);
  float inv_q = 1.0f / fmaxf(sqrtf(nq2), 1e-12f);
  float* simb = sim + (size_t)b * DD * HW + h * IMG_W + w;
  for (int d = 0; d < 32; d++){
    float pos = (float)w + displ[d] * direct * (float)(IMG_W - 1);
    pos = fminf(fmaxf(pos, 0.0f), (float)(IMG_W - 1));
    int x0 = (int)pos;
    int x1 = min(x0 + 1, IMG_W - 1);
    half_t tt = (half_t)(pos - (float)x0);
    f16x2 t2 = {tt, tt};
    U16 k0u, k1u;
    const uint4* r0 = &klds4[x0 * 5];
    const uint4* r1 = &klds4[x1 * 5];
    #pragma unroll
    for (int j = 0; j < 4; j++){ k0u.u4[j] = r0[j]; k1u.u4[j] = r1[j]; }
    float dot = 0.f, n2 = 0.f;
    #pragma unroll
    for (int i = 0; i < 16; i++){
      f16x2 wv = k0u.h2[i] + t2 * (k1u.h2[i] - k0u.h2[i]);
      dot = fdot2f(wv, qu.h2[i], dot);
      n2  = fdot2f(wv, wv, n2);
    }
    simb[d * HW] = dot * inv_q / fmaxf(sqrtf(n2), 1e-12f);
  }
}

// ---------------- K3: 3x3x3 cost conv + softmax_d + stats + f16 [pix][d] copy ----------------
__global__ __launch_bounds__(320) void k3_cost(
    const float* __restrict__ sim, const float* __restrict__ cf_w,
    float* __restrict__ norm_cost, half_t* __restrict__ ncp,
    double* __restrict__ csum, double* __restrict__ csq){
  __shared__ float w3[27];
  __shared__ float red1[5], red2[5];
  int tid = threadIdx.x;
  if (tid < 27) w3[tid] = cf_w[tid];
  __syncthreads();
  int b = blockIdx.y, h = blockIdx.x, w = tid;
  float cost[32];
  #pragma unroll
  for (int d = 0; d < 32; d++) cost[d] = 0.f;
  const float* sb = sim + (size_t)b * DD * HW;
  #pragma unroll
  for (int i = 0; i < 3; i++){
    int hh = h + i - 1;
    if (hh < 0 || hh >= IMG_H) continue;
    #pragma unroll
    for (int j = 0; j < 3; j++){
      int ww = w + j - 1;
      bool ok = (ww >= 0 && ww < IMG_W);
      const float* col = sb + hh * IMG_W + (ok ? ww : 0);
      float w0 = w3[0*9 + i*3 + j], w1 = w3[1*9 + i*3 + j], w2 = w3[2*9 + i*3 + j];
      #pragma unroll
      for (int e = 0; e < 32; e++){
        float v = ok ? col[e * HW] : 0.f;
        if (e < 31) cost[e+1] += w0 * v;
        cost[e] += w1 * v;
        if (e > 0)  cost[e-1] += w2 * v;
      }
    }
  }
  float mx = cost[0];
  #pragma unroll
  for (int d = 1; d < 32; d++) mx = fmaxf(mx, cost[d]);
  float s = 0.f;
  #pragma unroll
  for (int d = 0; d < 32; d++){ cost[d] = expf(cost[d] - mx); s += cost[d]; }
  float inv = 1.0f / s;
  float s1 = 0.f, s2 = 0.f;
  float* nb = norm_cost + (size_t)b * DD * HW + h * IMG_W + w;
  #pragma unroll
  for (int d = 0; d < 32; d++){
    float nc = cost[d] * inv;
    cost[d] = nc;
    nb[d * HW] = nc;
    s1 += nc; s2 += nc * nc;
  }
  // pack f16 [pix][d]
  {
    union { f16x2 h2[16]; uint4 u4[4]; } u;
    #pragma unroll
    for (int i = 0; i < 16; i++) u.h2[i] = f16x2{(half_t)cost[2*i], (half_t)cost[2*i+1]};
    uint4* dst = (uint4*)(ncp + (size_t)(b * HW + h * IMG_W + w) * 32);
    dst[0] = u.u4[0]; dst[1] = u.u4[1]; dst[2] = u.u4[2]; dst[3] = u.u4[3];
  }
  #pragma unroll
  for (int off = 32; off > 0; off >>= 1){ s1 += __shfl_down(s1, off, 64); s2 += __shfl_down(s2, off, 64); }
  int lane = tid & 63, wid = tid >> 6;
  if (lane == 0){ red1[wid] = s1; red2[wid] = s2; }
  __syncthreads();
  if (tid == 0){
    double a1 = 0, a2 = 0;
    for (int i = 0; i < 5; i++){ a1 += red1[i]; a2 += red2[i]; }
    atomicAdd(&csum[b], a1);
    atomicAdd(&csq[b], a2);
  }
}

// ---------------- K3.5: per-batch constant folding ----------------
__global__ __launch_bounds__(256) void k35_prep(
    const float* __restrict__ ce_w, const float* __restrict__ ce_b,
    const float* __restrict__ nt_w, const float* __restrict__ nt_b,
    const float* __restrict__ nc_w, const float* __restrict__ nc_b,
    const float* __restrict__ fa_w, const float* __restrict__ fa_b,
    const double* __restrict__ tsum, const double* __restrict__ tsq,
    const double* __restrict__ csum, const double* __restrict__ csq,
    const float* __restrict__ gbuf, half_t* __restrict__ ap, float* __restrict__ biasp,
    float* __restrict__ tnA, float* __restrict__ tnB, float* __restrict__ h1g,
    float* __restrict__ gp, float* __restrict__ zc){
  int t = threadIdx.x;
  int b = t >> 7, o = t & 127;
  float mu_t  = (float)(tsum[b] * (1.0 / (128.0 * HW)));
  float var_t = (float)(tsq[b]  * (1.0 / (128.0 * HW))) - mu_t * mu_t;
  float inv_t = 1.0f / sqrtf(var_t + 1e-5f);
  float mu_c  = (float)(csum[b] * (1.0 / (32.0 * HW)));
  float var_c = (float)(csq[b]  * (1.0 / (32.0 * HW))) - mu_c * mu_c;
  float inv_c = 1.0f / sqrtf(var_c + 1e-5f);
  float bias = ce_b[o];
  half_t* apo = ap + (size_t)(b * 128 + o) * 32;
  for (int d = 0; d < 32; d++){
    float wv = ce_w[o * 32 + d];
    bias += wv * (nc_b[d] - nc_w[d] * inv_c * mu_c);
    apo[d] = (half_t)(wv * nc_w[d] * inv_c);
  }
  biasp[b * 128 + o] = bias;
  tnA[b * 128 + o] = inv_t * nt_w[o];
  tnB[b * 128 + o] = nt_b[o] - mu_t * inv_t * nt_w[o];
  h1g[b * 128 + o] = fa_w[o] * nt_w[o] * inv_t;
  if (o < 32) gp[b * 32 + o] = gbuf[o] * nc_w[o] * inv_c;
  if (o == 0){
    float z = gbuf[32] + gbuf[34] - mu_t * inv_t * gbuf[33] + fa_b[0];
    for (int d = 0; d < 32; d++) z += gbuf[d] * (nc_b[d] - nc_w[d] * inv_c * mu_c);
    zc[b] = z;
  }
}

// ---------------- K4: gated fusion via MFMA -> fused f16 [pix][c] ----------------
__global__ __launch_bounds__(256) void k4_fuse(
    const float* __restrict__ t_feat, const half_t* __restrict__ ncp,
    const half_t* __restrict__ ap, const float* __restrict__ biasp,
    const float* __restrict__ tnA, const float* __restrict__ tnB,
    const float* __restrict__ h1g, const float* __restrict__ gp,
    const float* __restrict__ zc, half_t* __restrict__ fused){
  __shared__ half_t cf[128 * 136];
  __shared__ float alphas[128];
  __shared__ float zred[256];
  __shared__ float biasl[128], tnAl[128], tnBl[128];
  int tid = threadIdx.x;
  int b = blockIdx.x / 240;
  int pix0 = (blockIdx.x % 240) * 128;
  int lane = tid & 63, wid = tid >> 6, quad = lane >> 4, l15 = lane & 15;
  if (tid < 128){
    biasl[tid] = biasp[b * 128 + tid];
    tnAl[tid] = tnA[b * 128 + tid];
    tnBl[tid] = tnB[b * 128 + tid];
  }
  {
    int px = tid & 127, hf = tid >> 7;
    const float* tf = t_feat + (size_t)b * CC * HW + pix0 + px;
    float z = 0.f;
    for (int c = hf * 64; c < hf * 64 + 64; c++) z += h1g[b * 128 + c] * tf[c * HW];
    if (hf == 0){
      const half_t* np = ncp + (size_t)(b * HW + pix0 + px) * 32;
      for (int d = 0; d < 32; d++) z += gp[b * 32 + d] * (float)np[d];
    }
    zred[tid] = z;
  }
  __syncthreads();
  if (tid < 128){
    float z = zred[tid] + zred[tid + 128] + zc[b];
    alphas[tid] = 1.0f / (1.0f + expf(-z));
  }
  // MFMA: cost_feat = A'(128x32) x nc(32 x 128px)
  f32x4 acc[8][2];
  #pragma unroll
  for (int mt = 0; mt < 8; mt++){ acc[mt][0] = (f32x4){0,0,0,0}; acc[mt][1] = (f32x4){0,0,0,0}; }
  f16x8 bfr[2];
  #pragma unroll
  for (int nt = 0; nt < 2; nt++)
    bfr[nt] = *(const f16x8*)&ncp[(size_t)(b * HW + pix0 + wid*32 + nt*16 + l15) * 32 + quad * 8];
  #pragma unroll
  for (int mt = 0; mt < 8; mt++){
    f16x8 a = *(const f16x8*)&ap[(size_t)(b * 128 + mt*16 + l15) * 32 + quad * 8];
    acc[mt][0] = __builtin_amdgcn_mfma_f32_16x16x32_f16(a, bfr[0], acc[mt][0], 0, 0, 0);
    acc[mt][1] = __builtin_amdgcn_mfma_f32_16x16x32_f16(a, bfr[1], acc[mt][1], 0, 0, 0);
  }
  #pragma unroll
  for (int mt = 0; mt < 8; mt++)
    #pragma unroll
    for (int nt = 0; nt < 2; nt++)
      #pragma unroll
      for (int r = 0; r < 4; r++){
        int o = mt*16 + quad*4 + r;
        cf[(wid*32 + nt*16 + l15) * 136 + o] = (half_t)(acc[mt][nt][r] + biasl[o]);
      }
  __syncthreads();
  {
    int px = (wid & 1) * 64 + lane;
    int ob = (wid >> 1) * 64;
    float al = alphas[px];
    const float* tf = t_feat + (size_t)b * CC * HW + pix0 + px;
    for (int oo = 0; oo < 64; oo++){
      int o = ob + oo;
      float tn = tf[o * HW] * tnAl[o] + tnBl[o];
      float c = (float)cf[px * 136 + o];
      cf[px * 136 + o] = (half_t)(al * (tn - c) + c);
    }
  }
  __syncthreads();
  {
    int px = tid >> 1, hf = tid & 1;
    const uint4* srow = (const uint4*)&cf[px * 136 + hf * 64];
    uint4* drow = (uint4*)(fused + (size_t)(b * HW + pix0 + px) * 128 + hf * 64);
    #pragma unroll
    for (int j = 0; j < 8; j++) drow[j] = srow[j];
  }
}

// ---------------- K5: 3x3 reflect conv 128->128, MFMA, dbuf weights via global_load_lds ------
__global__ __launch_bounds__(256, 1) void k5_conv(
    const half_t* __restrict__ fused, const half_t* __restrict__ wconv,
    const float* __restrict__ rc_b, float* __restrict__ xout, float* __restrict__ ysum){
  __shared__ half_t patch[10 * 34 * 136];   // [row][col][c] pad 136 — 92,480 B
  __shared__ half_t wlds[2][16384];         // 2 x 32 KB
  __shared__ float rcb[128];
  int tid = threadIdx.x;
  int b = blockIdx.z;
  int h0 = blockIdx.y * 8;
  int w0 = blockIdx.x * 32;
  int lane = tid & 63, wid = tid >> 6, quad = lane >> 4, l15 = lane & 15;
  if (tid < 128) rcb[tid] = rc_b[tid];

  // prefetch weight chunk 0
  {
    const half_t* g = wconv;
    #pragma unroll
    for (int i = 0; i < 8; i++) gld16(g + (i*256 + tid)*8, &wlds[0][(i*256 + tid)*8]);
  }
  // stage patch (reflect-padded), rows h0-1..h0+8, cols w0-1..w0+32
  for (int idx = tid; idx < 340 * 16; idx += 256){
    int pp = idx >> 4, j = idx & 15;
    int r = pp / 34, col = pp - r * 34;
    int hs = h0 + r - 1;  hs = hs < 0 ? 1 : (hs >= IMG_H ? 2*IMG_H - 2 - hs : hs);
    int ws = w0 + col - 1; ws = ws < 0 ? 1 : (ws >= IMG_W ? 2*IMG_W - 2 - ws : ws);
    const uint4* s = (const uint4*)(fused + (size_t)(b * HW + hs * IMG_W + ws) * 128) + j;
    *((uint4*)&patch[(r * 34 + col) * 136] + j) = *s;
  }
  __syncthreads();

  f32x4 acc[8][4];
  #pragma unroll
  for (int mt = 0; mt < 8; mt++)
    #pragma unroll
    for (int nt = 0; nt < 4; nt++) acc[mt][nt] = (f32x4){0.f,0.f,0.f,0.f};

  #pragma unroll
  for (int kh = 0; kh < 3; kh++){
    #pragma unroll
    for (int kw2 = 0; kw2 < 3; kw2++){
      int pos = kh * 3 + kw2;
      if (pos < 8){
        const half_t* g = wconv + (pos + 1) * 16384;
        half_t* lb = &wlds[(pos + 1) & 1][0];
        #pragma unroll
        for (int i = 0; i < 8; i++) gld16(g + (i*256 + tid)*8, lb + (i*256 + tid)*8);
      }
      const half_t* wb = &wlds[pos & 1][0];
      #pragma unroll
      for (int q4 = 0; q4 < 4; q4++){
        f16x8 A[8];
        #pragma unroll
        for (int mt = 0; mt < 8; mt++)
          A[mt] = *(const f16x8*)&wb[((q4*4 + quad)*128 + mt*16 + l15)*8];
        #pragma unroll
        for (int nt = 0; nt < 4; nt++){
          int prow = wid*2 + (nt >> 1) + kh;
          int pcol = (nt & 1)*16 + l15 + kw2;
          f16x8 B = *(const f16x8*)&patch[(prow*34 + pcol)*136 + q4*32 + quad*8];
          #pragma unroll
          for (int mt = 0; mt < 8; mt++)
            acc[mt][nt] = __builtin_amdgcn_mfma_f32_16x16x32_f16(A[mt], B, acc[mt][nt], 0, 0, 0);
        }
      }
      __syncthreads();   // waves done with wb; prefetched chunk pos+1 drained (vmcnt 0)
    }
  }

  // epilogue: bias, store x, SE partial sums
  #pragma unroll
  for (int mt = 0; mt < 8; mt++){
    float ysl[4] = {0.f, 0.f, 0.f, 0.f};
    #pragma unroll
    for (int nt = 0; nt < 4; nt++){
      int hh = h0 + wid*2 + (nt >> 1);
      int ww = w0 + (nt & 1)*16 + l15;
      #pragma unroll
      for (int r = 0; r < 4; r++){
        int o = mt*16 + quad*4 + r;
        float v = acc[mt][nt][r] + rcb[o];
        xout[((size_t)(b * CC + o) * IMG_H + hh) * IMG_W + ww] = v;
        float rv = v;
        rv += __shfl_xor(rv, 1, 64);
        rv += __shfl_xor(rv, 2, 64);
        rv += __shfl_xor(rv, 4, 64);
        rv += __shfl_xor(rv, 8, 64);
        ysl[r] += rv;
      }
    }
    if (l15 == 0){
      #pragma unroll
      for (int r = 0; r < 4; r++) atomicAdd(&ysum[b * CC + mt*16 + quad*4 + r], ysl[r]);
    }
  }
}

// ---------------- K6: SE MLP ----------------
__global__ __launch_bounds__(256) void k6_se(
    const float* __restrict__ ysum, const float* __restrict__ se_w1,
    const float* __restrict__ se_w2, float* __restrict__ sescale){
  __shared__ float ym[256];
  __shared__ float y1[16];
  int t = threadIdx.x;
  ym[t] = ysum[t] * (1.0f / (float)HW);
  __syncthreads();
  if (t < 16){
    int b = t >> 3, j = t & 7;
    float a = 0.f;
    for (int o = 0; o < 128; o++) a += ym[b * 128 + o] * se_w1[j * 128 + o];
    y1[t] = fmaxf(a, 0.f);
  }
  __syncthreads();
  int b = t >> 7, o = t & 127;
  float a = 0.f;
  #pragma unroll
  for (int j = 0; j < 8; j++) a += y1[b * 8 + j] * se_w2[o * 8 + j];
  sescale[t] = 1.0f / (1.0f + expf(-a));
}

// ---------------- K7: x = elu(x * scale), in place ----------------
__global__ __launch_bounds__(256) void k7_elu(float* __restrict__ x, const float* __restrict__ sescale){
  int i4 = blockIdx.x * 256 + threadIdx.x;
  float4* xp = (float4*)x;
  float4 v = xp[i4];
  float s = sescale[i4 / 7680];
  float a = v.x * s, bb = v.y * s, c = v.z * s, d = v.w * s;
  v.x = a  > 0.f ? a  : expm1f(a);
  v.y = bb > 0.f ? bb : expm1f(bb);
  v.z = c  > 0.f ? c  : expm1f(c);
  v.w = d  > 0.f ? d  : expm1f(d);
  xp[i4] = v;
}

extern "C" void kernel_launch(void* const* d_in, const int* in_sizes, int n_in,
                              void* d_out, int out_size, void* d_ws, size_t ws_size,
                              hipStream_t stream){
  const float* t_feat = (const float*)d_in[0];
  const float* s_feat = (const float*)d_in[1];
  const float* directs = (const float*)d_in[2];
  const float* disp   = (const float*)d_in[3];
  const float* q_w = (const float*)d_in[4];
  const float* q_b = (const float*)d_in[5];
  const float* k_w = (const float*)d_in[6];
  const float* k_b = (const float*)d_in[7];
  const float* cf_w = (const float*)d_in[8];
  // d_in[9] = cf_b: softmax is shift-invariant, unused
  const float* nt_w = (const float*)d_in[10];
  const float* nt_b = (const float*)d_in[11];
  const float* nc_w = (const float*)d_in[12];
  const float* nc_b = (const float*)d_in[13];
  const float* ce_w = (const float*)d_in[14];
  const float* ce_b = (const float*)d_in[15];
  const float* fa_w = (const float*)d_in[16];
  const float* fa_b = (const float*)d_in[17];
  const float* rc_w = (const float*)d_in[18];
  const float* rc_b = (const float*)d_in[19];
  const float* se_w1 = (const float*)d_in[20];
  const float* se_w2 = (const float*)d_in[21];

  char* ws = (char*)d_ws;
  half_t* qbuf  = (half_t*)(ws + OFF_Q);
  half_t* kbuf  = (half_t*)(ws + OFF_K);
  float*  sim   = (float*)(ws + OFF_SIM);
  half_t* ncp   = (half_t*)(ws + OFF_NCP);
  half_t* fused = (half_t*)(ws + OFF_FUSED);
  half_t* wconv = (half_t*)(ws + OFF_WC);
  half_t* wqk   = (half_t*)(ws + OFF_WQK);
  half_t* ap    = (half_t*)(ws + OFF_AP);
  float*  biasp = (float*)(ws + OFF_MISC);
  float*  tnA   = (float*)(ws + OFF_MISC + 1024);
  float*  tnB   = (float*)(ws + OFF_MISC + 2048);
  float*  h1g   = (float*)(ws + OFF_MISC + 3072);
  float*  gp    = (float*)(ws + OFF_MISC + 4096);
  float*  zc    = (float*)(ws + OFF_MISC + 4352);
  char* st = ws + OFF_ST;
  double* tsum = (double*)(st + 0);
  double* tsq  = (double*)(st + 16);
  double* csum = (double*)(st + 32);
  double* csq  = (double*)(st + 48);
  float* ysum  = (float*)(st + 64);      // 256 f32
  float* sescale = (float*)(st + 1088);  // 256 f32
  float* gbuf  = (float*)(st + 2112);    // 64 f32

  float* xout = (float*)d_out;
  float* norm_cost = (float*)d_out + 7864320;

  hipMemsetAsync(st, 0, 1088, stream);
  k0_prep<<<610, 256, 0, stream>>>(rc_w, q_w, k_w, ce_w, ce_b, fa_w, nt_w, nt_b, wconv, wqk, gbuf);
  k1_qk<<<240, 256, 0, stream>>>(t_feat, s_feat, wqk, q_b, k_b, qbuf, kbuf, tsum, tsq);
  k2_sim<<<dim3(96, 2), 320, 0, stream>>>(qbuf, kbuf, directs, disp, sim);
  k3_cost<<<dim3(96, 2), 320, 0, stream>>>(sim, cf_w, norm_cost, ncp, csum, csq);
  k35_prep<<<1, 256, 0, stream>>>(ce_w, ce_b, nt_w, nt_b, nc_w, nc_b, fa_w, fa_b,
                                  tsum, tsq, csum, csq, gbuf, ap, biasp, tnA, tnB, h1g, gp, zc);
  k4_fuse<<<480, 256, 0, stream>>>(t_feat, ncp, ap, biasp, tnA, tnB, h1g, gp, zc, fused);
  k5_conv<<<dim3(10, 12, 2), 256, 0, stream>>>(fused, wconv, rc_b, xout, ysum);
  k6_se<<<1, 256, 0, stream>>>(ysum, se_w1, se_w2, sescale);
  k7_elu<<<7680, 256, 0, stream>>>(xout, sescale);
}

// Round 3
// 305.451 us; speedup vs baseline: 1.4400x; 1.1233x over previous
//
#include <hip/hip_runtime.h>
#include <stdint.h>

#define CC    128
#define CQn   32
#define DD    32
#define IMG_H 96
#define IMG_W 320
#define HW    30720
#define NPIX  61440

// workspace byte offsets
#define OFF_Q     0            // q f16 [2][30720][32]  = 3,932,160 B
#define OFF_K     3932160      // k f16                 = 3,932,160 B
#define OFF_SIM   7864320      // sim f32 [2][32][96][320] = 7,864,320 B
#define OFF_NCP   15728640     // norm_cost f16 [2][30720][32] = 3,932,160 B
#define OFF_FUSED 0            // fused f16 [61440][128] = 15,728,640 B (aliases q/k/sim)
#define OFF_WC    19660800     // conv weights f16, 294,912 B
#define OFF_WQK   19955712     // q_w/k_w f16, 16,384 B
#define OFF_AP    19972096     // A' f16 [2][128][32], 16,384 B
#define OFF_MISC  19988480     // f32: biasp[256],tnA[256],tnB[256],h1g[256],gp[64],zc[2]
#define OFF_ST    20000768     // stats

typedef _Float16 half_t;
typedef _Float16 f16x2 __attribute__((ext_vector_type(2)));
typedef _Float16 f16x8 __attribute__((ext_vector_type(8)));
typedef float    f32x4 __attribute__((ext_vector_type(4)));

__device__ __forceinline__ float fdot2f(f16x2 a, f16x2 b, float c){
#if __has_builtin(__builtin_amdgcn_fdot2)
  return __builtin_amdgcn_fdot2(a, b, c, false);
#else
  return c + (float)a.x*(float)b.x + (float)a.y*(float)b.y;
#endif
}

// ---------------- K0: weight prep (conv weights re-layout + qk weights f16 + gate constants) ----
__global__ __launch_bounds__(256) void k0_prep(
    const float* __restrict__ rc_w, const float* __restrict__ q_w, const float* __restrict__ k_w,
    const float* __restrict__ ce_w, const float* __restrict__ ce_b,
    const float* __restrict__ fa_w, const float* __restrict__ nt_w, const float* __restrict__ nt_b,
    half_t* __restrict__ wconv, half_t* __restrict__ wqk, float* __restrict__ gbuf){
  int blk = blockIdx.x, tid = threadIdx.x;
  if (blk < 576){
    // wconv[((pos*16 + q4*4 + kq)*128 + o)*8 + j] = rc_w[o][c][pos], c = q4*32+kq*8+j
    int idx = blk * 256 + tid;                 // 0..147455
    int j = idx & 7;
    int o = (idx >> 3) & 127;
    int g = idx >> 10;                          // 0..143
    int kq = g & 3, q4 = (g >> 2) & 3, pos = g >> 4;
    int c = q4*32 + kq*8 + j;
    wconv[idx] = (half_t)rc_w[(o*128 + c)*9 + pos];
  } else if (blk < 608){
    int idx = (blk - 576) * 256 + tid;          // 0..8191
    wqk[idx] = (half_t)(idx < 4096 ? q_w[idx] : k_w[idx - 4096]);
  } else {
    int t = tid;
    if (t < 32){
      float a = 0.f;
      for (int o = 0; o < 128; o++) a += fa_w[128 + o] * ce_w[o * 32 + t];
      gbuf[t] = a;
    } else if (t == 32){
      float a = 0.f;
      for (int o = 0; o < 128; o++) a += fa_w[128 + o] * ce_b[o];
      gbuf[32] = a;
    } else if (t == 33){
      float a = 0.f;
      for (int c = 0; c < 128; c++) a += fa_w[c] * nt_w[c];
      gbuf[33] = a;
    } else if (t == 34){
      float a = 0.f;
      for (int c = 0; c < 128; c++) a += fa_w[c] * nt_b[c];
      gbuf[34] = a;
    }
  }
}

// ---------------- K1: q/k projections via MFMA + t_feat stats -> q,k f16 [b][pix][32] ---------
// 128-pixel tiles, feat LDS 35 KB (outs aliased into feat) -> 4 blocks/CU
__global__ __launch_bounds__(256) void k1_qk(
    const float* __restrict__ t_feat, const float* __restrict__ s_feat,
    const half_t* __restrict__ wqk, const float* __restrict__ q_b, const float* __restrict__ k_b,
    half_t* __restrict__ qbuf, half_t* __restrict__ kbuf,
    double* __restrict__ tsum, double* __restrict__ tsq){
  __shared__ half_t feat[128 * 136];    // [px][c] pad 136; out (32 halves/px) aliased in-row
  __shared__ float red1[4], red2[4];
  __shared__ float qbl[32], kbl[32];
  int tid = threadIdx.x;
  int b = blockIdx.x / 240;
  int pix0 = (blockIdx.x % 240) * 128;
  int lane = tid & 63, wid = tid >> 6;
  int quad = lane >> 4, l15 = lane & 15;
  if (tid < 32){ qbl[tid] = q_b[tid]; kbl[tid] = k_b[tid]; }
  int px_s = tid & 127, hf = tid >> 7;      // staging: 2 threads per pixel

  for (int phase = 0; phase < 2; phase++){
    const float* src = (phase == 0 ? t_feat : s_feat) + (size_t)b * CC * HW + pix0 + px_s;
    float s1 = 0.f, s2 = 0.f;
    for (int c = hf * 64; c < hf * 64 + 64; c += 2){
      float v0 = src[c * HW], v1 = src[(c + 1) * HW];
      if (phase == 0){ s1 += v0 + v1; s2 += v0 * v0 + v1 * v1; }
      *(f16x2*)&feat[px_s * 136 + c] = f16x2{(half_t)v0, (half_t)v1};
    }
    if (phase == 0){
      #pragma unroll
      for (int off = 32; off > 0; off >>= 1){ s1 += __shfl_down(s1, off, 64); s2 += __shfl_down(s2, off, 64); }
      if (lane == 0){ red1[wid] = s1; red2[wid] = s2; }
    }
    __syncthreads();
    if (phase == 0 && tid == 0){
      atomicAdd(&tsum[b], (double)red1[0] + red1[1] + red1[2] + red1[3]);
      atomicAdd(&tsq[b],  (double)red2[0] + red2[1] + red2[2] + red2[3]);
    }
    // MFMA: out(32 x 128px) = W(32x128) * feat(128 x 128px); wave wid owns px [wid*32, wid*32+32)
    const half_t* W = wqk + phase * 4096;
    f32x4 acc[2][2];
    #pragma unroll
    for (int m = 0; m < 2; m++){ acc[m][0] = (f32x4){0,0,0,0}; acc[m][1] = (f32x4){0,0,0,0}; }
    #pragma unroll
    for (int q4 = 0; q4 < 4; q4++){
      f16x8 a0 = *(const f16x8*)&W[(l15) * 128 + q4*32 + quad*8];
      f16x8 a1 = *(const f16x8*)&W[(16 + l15) * 128 + q4*32 + quad*8];
      #pragma unroll
      for (int nt = 0; nt < 2; nt++){
        f16x8 bf = *(const f16x8*)&feat[(wid*32 + nt*16 + l15) * 136 + q4*32 + quad*8];
        acc[0][nt] = __builtin_amdgcn_mfma_f32_16x16x32_f16(a0, bf, acc[0][nt], 0, 0, 0);
        acc[1][nt] = __builtin_amdgcn_mfma_f32_16x16x32_f16(a1, bf, acc[1][nt], 0, 0, 0);
      }
    }
    const float* bl = phase == 0 ? qbl : kbl;
    // write results into own rows of feat (wave-private region; in-wave LDS ordering is safe)
    #pragma unroll
    for (int m = 0; m < 2; m++)
      #pragma unroll
      for (int nt = 0; nt < 2; nt++)
        #pragma unroll
        for (int r = 0; r < 4; r++){
          int o = m*16 + quad*4 + r;
          feat[(wid*32 + nt*16 + l15) * 136 + o] = (half_t)(acc[m][nt][r] + bl[o]);
        }
    __syncthreads();
    {
      half_t* dst = (phase == 0 ? qbuf : kbuf) + (size_t)(b * HW + pix0 + px_s) * 32;
      if (hf == 0){
        uint4* d4 = (uint4*)dst;
        const uint4* s4 = (const uint4*)&feat[px_s * 136];
        d4[0] = s4[0]; d4[1] = s4[1]; d4[2] = s4[2]; d4[3] = s4[3];
      }
    }
    __syncthreads();
  }
}

// ---------------- K2: warp + cosine sim volume (f16 packed math) ----------------
__global__ __launch_bounds__(320) void k2_sim(
    const half_t* __restrict__ qbuf, const half_t* __restrict__ kbuf,
    const float* __restrict__ directs, const float* __restrict__ disp,
    float* __restrict__ sim){
  __shared__ uint4 klds4[320 * 5];     // [x][4 data + 1 pad] = 64B rows padded to 80B
  __shared__ float displ[32];
  int tid = threadIdx.x;
  int b = blockIdx.y, h = blockIdx.x;
  for (int u = tid; u < 1280; u += 320){
    int x = u >> 2, j = u & 3;
    klds4[x * 5 + j] = ((const uint4*)(kbuf + (size_t)(b * HW + h * IMG_W + x) * 32))[j];
  }
  if (tid < 32) displ[tid] = disp[tid];
  __syncthreads();
  int w = tid;
  float direct = directs[b];
  union U16 { uint4 u4[4]; f16x2 h2[16]; };
  U16 qu;
  {
    const uint4* qp = (const uint4*)(qbuf + (size_t)(b * HW + h * IMG_W + w) * 32);
    qu.u4[0] = qp[0]; qu.u4[1] = qp[1]; qu.u4[2] = qp[2]; qu.u4[3] = qp[3];
  }
  float nq2 = 0.f;
  #pragma unroll
  for (int i = 0; i < 16; i++) nq2 = fdot2f(qu.h2[i], qu.h2[i], nq2);
  float inv_q = 1.0f / fmaxf(sqrtf(nq2), 1e-12f);
  float* simb = sim + (size_t)b * DD * HW + h * IMG_W + w;
  for (int d = 0; d < 32; d++){
    float pos = (float)w + displ[d] * direct * (float)(IMG_W - 1);
    pos = fminf(fmaxf(pos, 0.0f), (float)(IMG_W - 1));
    int x0 = (int)pos;
    int x1 = min(x0 + 1, IMG_W - 1);
    half_t tt = (half_t)(pos - (float)x0);
    f16x2 t2 = {tt, tt};
    U16 k0u, k1u;
    const uint4* r0 = &klds4[x0 * 5];
    const uint4* r1 = &klds4[x1 * 5];
    #pragma unroll
    for (int j = 0; j < 4; j++){ k0u.u4[j] = r0[j]; k1u.u4[j] = r1[j]; }
    float dot = 0.f, n2 = 0.f;
    #pragma unroll
    for (int i = 0; i < 16; i++){
      f16x2 wv = k0u.h2[i] + t2 * (k1u.h2[i] - k0u.h2[i]);
      dot = fdot2f(wv, qu.h2[i], dot);
      n2  = fdot2f(wv, wv, n2);
    }
    simb[d * HW] = dot * inv_q / fmaxf(sqrtf(n2), 1e-12f);
  }
}

// ---------------- K3: 3x3x3 cost conv + softmax_d + stats + f16 [pix][d] copy ----------------
__global__ __launch_bounds__(320) void k3_cost(
    const float* __restrict__ sim, const float* __restrict__ cf_w,
    float* __restrict__ norm_cost, half_t* __restrict__ ncp,
    double* __restrict__ csum, double* __restrict__ csq){
  __shared__ float w3[27];
  __shared__ float red1[5], red2[5];
  int tid = threadIdx.x;
  if (tid < 27) w3[tid] = cf_w[tid];
  __syncthreads();
  int b = blockIdx.y, h = blockIdx.x, w = tid;
  float cost[32];
  #pragma unroll
  for (int d = 0; d < 32; d++) cost[d] = 0.f;
  const float* sb = sim + (size_t)b * DD * HW;
  #pragma unroll
  for (int i = 0; i < 3; i++){
    int hh = h + i - 1;
    if (hh < 0 || hh >= IMG_H) continue;
    #pragma unroll
    for (int j = 0; j < 3; j++){
      int ww = w + j - 1;
      bool ok = (ww >= 0 && ww < IMG_W);
      const float* col = sb + hh * IMG_W + (ok ? ww : 0);
      float w0 = w3[0*9 + i*3 + j], w1 = w3[1*9 + i*3 + j], w2 = w3[2*9 + i*3 + j];
      #pragma unroll
      for (int e = 0; e < 32; e++){
        float v = ok ? col[e * HW] : 0.f;
        if (e < 31) cost[e+1] += w0 * v;
        cost[e] += w1 * v;
        if (e > 0)  cost[e-1] += w2 * v;
      }
    }
  }
  float mx = cost[0];
  #pragma unroll
  for (int d = 1; d < 32; d++) mx = fmaxf(mx, cost[d]);
  float s = 0.f;
  #pragma unroll
  for (int d = 0; d < 32; d++){ cost[d] = expf(cost[d] - mx); s += cost[d]; }
  float inv = 1.0f / s;
  float s1 = 0.f, s2 = 0.f;
  float* nb = norm_cost + (size_t)b * DD * HW + h * IMG_W + w;
  #pragma unroll
  for (int d = 0; d < 32; d++){
    float nc = cost[d] * inv;
    cost[d] = nc;
    nb[d * HW] = nc;
    s1 += nc; s2 += nc * nc;
  }
  // pack f16 [pix][d]
  {
    union { f16x2 h2[16]; uint4 u4[4]; } u;
    #pragma unroll
    for (int i = 0; i < 16; i++) u.h2[i] = f16x2{(half_t)cost[2*i], (half_t)cost[2*i+1]};
    uint4* dst = (uint4*)(ncp + (size_t)(b * HW + h * IMG_W + w) * 32);
    dst[0] = u.u4[0]; dst[1] = u.u4[1]; dst[2] = u.u4[2]; dst[3] = u.u4[3];
  }
  #pragma unroll
  for (int off = 32; off > 0; off >>= 1){ s1 += __shfl_down(s1, off, 64); s2 += __shfl_down(s2, off, 64); }
  int lane = tid & 63, wid = tid >> 6;
  if (lane == 0){ red1[wid] = s1; red2[wid] = s2; }
  __syncthreads();
  if (tid == 0){
    double a1 = 0, a2 = 0;
    for (int i = 0; i < 5; i++){ a1 += red1[i]; a2 += red2[i]; }
    atomicAdd(&csum[b], a1);
    atomicAdd(&csq[b], a2);
  }
}

// ---------------- K3.5: per-batch constant folding ----------------
__global__ __launch_bounds__(256) void k35_prep(
    const float* __restrict__ ce_w, const float* __restrict__ ce_b,
    const float* __restrict__ nt_w, const float* __restrict__ nt_b,
    const float* __restrict__ nc_w, const float* __restrict__ nc_b,
    const float* __restrict__ fa_w, const float* __restrict__ fa_b,
    const double* __restrict__ tsum, const double* __restrict__ tsq,
    const double* __restrict__ csum, const double* __restrict__ csq,
    const float* __restrict__ gbuf, half_t* __restrict__ ap, float* __restrict__ biasp,
    float* __restrict__ tnA, float* __restrict__ tnB, float* __restrict__ h1g,
    float* __restrict__ gp, float* __restrict__ zc){
  int t = threadIdx.x;
  int b = t >> 7, o = t & 127;
  float mu_t  = (float)(tsum[b] * (1.0 / (128.0 * HW)));
  float var_t = (float)(tsq[b]  * (1.0 / (128.0 * HW))) - mu_t * mu_t;
  float inv_t = 1.0f / sqrtf(var_t + 1e-5f);
  float mu_c  = (float)(csum[b] * (1.0 / (32.0 * HW)));
  float var_c = (float)(csq[b]  * (1.0 / (32.0 * HW))) - mu_c * mu_c;
  float inv_c = 1.0f / sqrtf(var_c + 1e-5f);
  float bias = ce_b[o];
  half_t* apo = ap + (size_t)(b * 128 + o) * 32;
  for (int d = 0; d < 32; d++){
    float wv = ce_w[o * 32 + d];
    bias += wv * (nc_b[d] - nc_w[d] * inv_c * mu_c);
    apo[d] = (half_t)(wv * nc_w[d] * inv_c);
  }
  biasp[b * 128 + o] = bias;
  tnA[b * 128 + o] = inv_t * nt_w[o];
  tnB[b * 128 + o] = nt_b[o] - mu_t * inv_t * nt_w[o];
  h1g[b * 128 + o] = fa_w[o] * nt_w[o] * inv_t;
  if (o < 32) gp[b * 32 + o] = gbuf[o] * nc_w[o] * inv_c;
  if (o == 0){
    float z = gbuf[32] + gbuf[34] - mu_t * inv_t * gbuf[33] + fa_b[0];
    for (int d = 0; d < 32; d++) z += gbuf[d] * (nc_b[d] - nc_w[d] * inv_c * mu_c);
    zc[b] = z;
  }
}

// ---------------- K4: gated fusion via MFMA -> fused f16 [pix][c] ----------------
__global__ __launch_bounds__(256) void k4_fuse(
    const float* __restrict__ t_feat, const half_t* __restrict__ ncp,
    const half_t* __restrict__ ap, const float* __restrict__ biasp,
    const float* __restrict__ tnA, const float* __restrict__ tnB,
    const float* __restrict__ h1g, const float* __restrict__ gp,
    const float* __restrict__ zc, half_t* __restrict__ fused){
  __shared__ half_t cf[128 * 136];
  __shared__ float alphas[128];
  __shared__ float zred[256];
  __shared__ float biasl[128], tnAl[128], tnBl[128];
  int tid = threadIdx.x;
  int b = blockIdx.x / 240;
  int pix0 = (blockIdx.x % 240) * 128;
  int lane = tid & 63, wid = tid >> 6, quad = lane >> 4, l15 = lane & 15;
  if (tid < 128){
    biasl[tid] = biasp[b * 128 + tid];
    tnAl[tid] = tnA[b * 128 + tid];
    tnBl[tid] = tnB[b * 128 + tid];
  }
  {
    int px = tid & 127, hf = tid >> 7;
    const float* tf = t_feat + (size_t)b * CC * HW + pix0 + px;
    float z = 0.f;
    for (int c = hf * 64; c < hf * 64 + 64; c++) z += h1g[b * 128 + c] * tf[c * HW];
    if (hf == 0){
      const half_t* np = ncp + (size_t)(b * HW + pix0 + px) * 32;
      for (int d = 0; d < 32; d++) z += gp[b * 32 + d] * (float)np[d];
    }
    zred[tid] = z;
  }
  __syncthreads();
  if (tid < 128){
    float z = zred[tid] + zred[tid + 128] + zc[b];
    alphas[tid] = 1.0f / (1.0f + expf(-z));
  }
  // MFMA: cost_feat = A'(128x32) x nc(32 x 128px)
  f32x4 acc[8][2];
  #pragma unroll
  for (int mt = 0; mt < 8; mt++){ acc[mt][0] = (f32x4){0,0,0,0}; acc[mt][1] = (f32x4){0,0,0,0}; }
  f16x8 bfr[2];
  #pragma unroll
  for (int nt = 0; nt < 2; nt++)
    bfr[nt] = *(const f16x8*)&ncp[(size_t)(b * HW + pix0 + wid*32 + nt*16 + l15) * 32 + quad * 8];
  #pragma unroll
  for (int mt = 0; mt < 8; mt++){
    f16x8 a = *(const f16x8*)&ap[(size_t)(b * 128 + mt*16 + l15) * 32 + quad * 8];
    acc[mt][0] = __builtin_amdgcn_mfma_f32_16x16x32_f16(a, bfr[0], acc[mt][0], 0, 0, 0);
    acc[mt][1] = __builtin_amdgcn_mfma_f32_16x16x32_f16(a, bfr[1], acc[mt][1], 0, 0, 0);
  }
  #pragma unroll
  for (int mt = 0; mt < 8; mt++)
    #pragma unroll
    for (int nt = 0; nt < 2; nt++)
      #pragma unroll
      for (int r = 0; r < 4; r++){
        int o = mt*16 + quad*4 + r;
        cf[(wid*32 + nt*16 + l15) * 136 + o] = (half_t)(acc[mt][nt][r] + biasl[o]);
      }
  __syncthreads();
  {
    int px = (wid & 1) * 64 + lane;
    int ob = (wid >> 1) * 64;
    float al = alphas[px];
    const float* tf = t_feat + (size_t)b * CC * HW + pix0 + px;
    for (int oo = 0; oo < 64; oo++){
      int o = ob + oo;
      float tn = tf[o * HW] * tnAl[o] + tnBl[o];
      float c = (float)cf[px * 136 + o];
      cf[px * 136 + o] = (half_t)(al * (tn - c) + c);
    }
  }
  __syncthreads();
  {
    int px = tid >> 1, hf = tid & 1;
    const uint4* srow = (const uint4*)&cf[px * 136 + hf * 64];
    uint4* drow = (uint4*)(fused + (size_t)(b * HW + pix0 + px) * 128 + hf * 64);
    #pragma unroll
    for (int j = 0; j < 8; j++) drow[j] = srow[j];
  }
}

// ---------------- K5: 3x3 reflect conv 128->128, MFMA; weights direct-from-global (L2),
// patch-only LDS (55 KB -> 2 blocks/CU), barrier-free K-loop ----------------
__global__ __launch_bounds__(256, 2) void k5_conv(
    const half_t* __restrict__ fused, const half_t* __restrict__ wconv,
    const float* __restrict__ rc_b, float* __restrict__ xout, float* __restrict__ ysum){
  __shared__ half_t patch[6 * 34 * 136];   // [row][col][c] pad 136 — 55,488 B
  __shared__ float rcb[128];
  int tid = threadIdx.x;
  int b = blockIdx.z;
  int h0 = blockIdx.y * 4;
  int w0 = blockIdx.x * 32;
  int lane = tid & 63, wid = tid >> 6, quad = lane >> 4, l15 = lane & 15;
  if (tid < 128) rcb[tid] = rc_b[tid];

  // stage patch (reflect-padded): rows h0-1..h0+4, cols w0-1..w0+32
  for (int idx = tid; idx < 204 * 16; idx += 256){
    int pp = idx >> 4, j = idx & 15;
    int r = pp / 34, col = pp - r * 34;
    int hs = h0 + r - 1;  hs = hs < 0 ? 1 : (hs >= IMG_H ? 2*IMG_H - 2 - hs : hs);
    int ws = w0 + col - 1; ws = ws < 0 ? 1 : (ws >= IMG_W ? 2*IMG_W - 2 - ws : ws);
    const uint4* s = (const uint4*)(fused + (size_t)(b * HW + hs * IMG_W + ws) * 128) + j;
    *((uint4*)&patch[(r * 34 + col) * 136] + j) = *s;
  }
  __syncthreads();

  // wave wid owns outputs o in [wid*32, wid*32+32): local m-tiles mt=0,1
  f32x4 acc[2][8];
  #pragma unroll
  for (int mt = 0; mt < 2; mt++)
    #pragma unroll
    for (int nt = 0; nt < 8; nt++) acc[mt][nt] = (f32x4){0.f,0.f,0.f,0.f};

  for (int pos = 0; pos < 9; pos++){
    int kh = pos / 3;
    int kw2 = pos - kh * 3;
    #pragma unroll
    for (int q4 = 0; q4 < 4; q4++){
      const half_t* wrow = wconv + ((size_t)(pos*16 + q4*4 + quad) * 128 + wid*32 + l15) * 8;
      f16x8 A0 = *(const f16x8*)wrow;              // mt=0: o = wid*32 + l15
      f16x8 A1 = *(const f16x8*)(wrow + 128);      // mt=1: o = wid*32 + 16 + l15
      #pragma unroll
      for (int nt = 0; nt < 8; nt++){
        int hrow = nt >> 1, whalf = nt & 1;
        f16x8 B = *(const f16x8*)&patch[((hrow + kh)*34 + whalf*16 + l15 + kw2)*136 + q4*32 + quad*8];
        acc[0][nt] = __builtin_amdgcn_mfma_f32_16x16x32_f16(A0, B, acc[0][nt], 0, 0, 0);
        acc[1][nt] = __builtin_amdgcn_mfma_f32_16x16x32_f16(A1, B, acc[1][nt], 0, 0, 0);
      }
    }
  }

  // epilogue: bias, store x, SE partial sums
  #pragma unroll
  for (int mt = 0; mt < 2; mt++){
    float ysl[4] = {0.f, 0.f, 0.f, 0.f};
    #pragma unroll
    for (int nt = 0; nt < 8; nt++){
      int hh = h0 + (nt >> 1);
      int ww = w0 + (nt & 1)*16 + l15;
      #pragma unroll
      for (int r = 0; r < 4; r++){
        int o = wid*32 + mt*16 + quad*4 + r;
        float v = acc[mt][nt][r] + rcb[o];
        xout[((size_t)(b * CC + o) * IMG_H + hh) * IMG_W + ww] = v;
        float rv = v;
        rv += __shfl_xor(rv, 1, 64);
        rv += __shfl_xor(rv, 2, 64);
        rv += __shfl_xor(rv, 4, 64);
        rv += __shfl_xor(rv, 8, 64);
        ysl[r] += rv;
      }
    }
    if (l15 == 0){
      #pragma unroll
      for (int r = 0; r < 4; r++) atomicAdd(&ysum[b * CC + wid*32 + mt*16 + quad*4 + r], ysl[r]);
    }
  }
}

// ---------------- K6: SE MLP ----------------
__global__ __launch_bounds__(256) void k6_se(
    const float* __restrict__ ysum, const float* __restrict__ se_w1,
    const float* __restrict__ se_w2, float* __restrict__ sescale){
  __shared__ float ym[256];
  __shared__ float y1[16];
  int t = threadIdx.x;
  ym[t] = ysum[t] * (1.0f / (float)HW);
  __syncthreads();
  if (t < 16){
    int b = t >> 3, j = t & 7;
    float a = 0.f;
    for (int o = 0; o < 128; o++) a += ym[b * 128 + o] * se_w1[j * 128 + o];
    y1[t] = fmaxf(a, 0.f);
  }
  __syncthreads();
  int b = t >> 7, o = t & 127;
  float a = 0.f;
  #pragma unroll
  for (int j = 0; j < 8; j++) a += y1[b * 8 + j] * se_w2[o * 8 + j];
  sescale[t] = 1.0f / (1.0f + expf(-a));
}

// ---------------- K7: x = elu(x * scale), in place ----------------
__global__ __launch_bounds__(256) void k7_elu(float* __restrict__ x, const float* __restrict__ sescale){
  int i4 = blockIdx.x * 256 + threadIdx.x;
  float4* xp = (float4*)x;
  float4 v = xp[i4];
  float s = sescale[i4 / 7680];
  float a = v.x * s, bb = v.y * s, c = v.z * s, d = v.w * s;
  v.x = a  > 0.f ? a  : expm1f(a);
  v.y = bb > 0.f ? bb : expm1f(bb);
  v.z = c  > 0.f ? c  : expm1f(c);
  v.w = d  > 0.f ? d  : expm1f(d);
  xp[i4] = v;
}

extern "C" void kernel_launch(void* const* d_in, const int* in_sizes, int n_in,
                              void* d_out, int out_size, void* d_ws, size_t ws_size,
                              hipStream_t stream){
  const float* t_feat = (const float*)d_in[0];
  const float* s_feat = (const float*)d_in[1];
  const float* directs = (const float*)d_in[2];
  const float* disp   = (const float*)d_in[3];
  const float* q_w = (const float*)d_in[4];
  const float* q_b = (const float*)d_in[5];
  const float* k_w = (const float*)d_in[6];
  const float* k_b = (const float*)d_in[7];
  const float* cf_w = (const float*)d_in[8];
  // d_in[9] = cf_b: softmax is shift-invariant, unused
  const float* nt_w = (const float*)d_in[10];
  const float* nt_b = (const float*)d_in[11];
  const float* nc_w = (const float*)d_in[12];
  const float* nc_b = (const float*)d_in[13];
  const float* ce_w = (const float*)d_in[14];
  const float* ce_b = (const float*)d_in[15];
  const float* fa_w = (const float*)d_in[16];
  const float* fa_b = (const float*)d_in[17];
  const float* rc_w = (const float*)d_in[18];
  const float* rc_b = (const float*)d_in[19];
  const float* se_w1 = (const float*)d_in[20];
  const float* se_w2 = (const float*)d_in[21];

  char* ws = (char*)d_ws;
  half_t* qbuf  = (half_t*)(ws + OFF_Q);
  half_t* kbuf  = (half_t*)(ws + OFF_K);
  float*  sim   = (float*)(ws + OFF_SIM);
  half_t* ncp   = (half_t*)(ws + OFF_NCP);
  half_t* fused = (half_t*)(ws + OFF_FUSED);
  half_t* wconv = (half_t*)(ws + OFF_WC);
  half_t* wqk   = (half_t*)(ws + OFF_WQK);
  half_t* ap    = (half_t*)(ws + OFF_AP);
  float*  biasp = (float*)(ws + OFF_MISC);
  float*  tnA   = (float*)(ws + OFF_MISC + 1024);
  float*  tnB   = (float*)(ws + OFF_MISC + 2048);
  float*  h1g   = (float*)(ws + OFF_MISC + 3072);
  float*  gp    = (float*)(ws + OFF_MISC + 4096);
  float*  zc    = (float*)(ws + OFF_MISC + 4352);
  char* st = ws + OFF_ST;
  double* tsum = (double*)(st + 0);
  double* tsq  = (double*)(st + 16);
  double* csum = (double*)(st + 32);
  double* csq  = (double*)(st + 48);
  float* ysum  = (float*)(st + 64);      // 256 f32
  float* sescale = (float*)(st + 1088);  // 256 f32
  float* gbuf  = (float*)(st + 2112);    // 64 f32

  float* xout = (float*)d_out;
  float* norm_cost = (float*)d_out + 7864320;

  hipMemsetAsync(st, 0, 1088, stream);
  k0_prep<<<610, 256, 0, stream>>>(rc_w, q_w, k_w, ce_w, ce_b, fa_w, nt_w, nt_b, wconv, wqk, gbuf);
  k1_qk<<<480, 256, 0, stream>>>(t_feat, s_feat, wqk, q_b, k_b, qbuf, kbuf, tsum, tsq);
  k2_sim<<<dim3(96, 2), 320, 0, stream>>>(qbuf, kbuf, directs, disp, sim);
  k3_cost<<<dim3(96, 2), 320, 0, stream>>>(sim, cf_w, norm_cost, ncp, csum, csq);
  k35_prep<<<1, 256, 0, stream>>>(ce_w, ce_b, nt_w, nt_b, nc_w, nc_b, fa_w, fa_b,
                                  tsum, tsq, csum, csq, gbuf, ap, biasp, tnA, tnB, h1g, gp, zc);
  k4_fuse<<<480, 256, 0, stream>>>(t_feat, ncp, ap, biasp, tnA, tnB, h1g, gp, zc, fused);
  k5_conv<<<dim3(10, 24, 2), 256, 0, stream>>>(fused, wconv, rc_b, xout, ysum);
  k6_se<<<1, 256, 0, stream>>>(ysum, se_w1, se_w2, sescale);
  k7_elu<<<7680, 256, 0, stream>>>(xout, sescale);
}